// Round 2
// baseline (1226.565 us; speedup 1.0000x reference)
//
#include <hip/hip_runtime.h>
#include <math.h>

#define EMB 1024
#define HID 1024
#define VOCAB 50257
#define HOUT_OFF VOCAB
#define COUT_OFF (VOCAB + 2*HID)
#define ROWS_PER_BLOCK 16
#define NB_LOGITS ((VOCAB + ROWS_PER_BLOCK - 1) / ROWS_PER_BLOCK)  // 3142
#define GRID_BLKS 1024   // 256 CUs * 4 blocks/CU; __launch_bounds__(256,4) guarantees co-residency

__device__ __forceinline__ float wave_reduce(float v) {
#pragma unroll
    for (int o = 32; o > 0; o >>= 1) v += __shfl_down(v, o);
    return v;
}

__device__ __forceinline__ float sigmoidf_(float x) { return 1.0f / (1.0f + expf(-x)); }

// Manual grid barrier: counter zeroed by hipMemsetAsync before launch.
// n-th use passes target = n * GRID_BLKS. Device-scope (AGENT) atomics
// cross the non-coherent per-XCD L2s; threadfence orders the plain
// data stores around the barrier.
__device__ __forceinline__ void grid_sync(unsigned* bar, unsigned target) {
    __threadfence();            // release all prior plain stores (agent scope)
    __syncthreads();            // whole block arrived
    if (threadIdx.x == 0) {
        __hip_atomic_fetch_add(bar, 1u, __ATOMIC_ACQ_REL, __HIP_MEMORY_SCOPE_AGENT);
        unsigned v;
        do {
            __builtin_amdgcn_s_sleep(1);
            v = __hip_atomic_load(bar, __ATOMIC_ACQUIRE, __HIP_MEMORY_SCOPE_AGENT);
        } while (v < target);
    }
    __syncthreads();
    __threadfence();            // acquire side for the other waves
}

// One block per hidden unit r; wave w computes gate w (i/f/g/o).
__device__ __forceinline__ void lstm_layer(
    const float* __restrict__ Wih, const float* __restrict__ Whh,
    const float* __restrict__ bih, const float* __restrict__ bhh,
    const float* __restrict__ x, bool relu_x,
    const float* __restrict__ h_prev, const float* __restrict__ c_prev,
    float* __restrict__ h_ws, float* __restrict__ out, int layer, int r)
{
    const int wave = threadIdx.x >> 6;
    const int lane = threadIdx.x & 63;
    const int row  = wave * HID + r;

    float4 xv[4], hv[4];
#pragma unroll
    for (int j = 0; j < 4; ++j) {
        float4 v = ((const float4*)x)[j*64 + lane];
        if (relu_x) {
            v.x = fmaxf(v.x, 0.f); v.y = fmaxf(v.y, 0.f);
            v.z = fmaxf(v.z, 0.f); v.w = fmaxf(v.w, 0.f);
        }
        xv[j] = v;
        hv[j] = ((const float4*)h_prev)[j*64 + lane];
    }

    const float4* wih = (const float4*)(Wih + (size_t)row * EMB);
    const float4* whh = (const float4*)(Whh + (size_t)row * HID);
    float acc = 0.f;
#pragma unroll
    for (int j = 0; j < 4; ++j) {
        float4 a = wih[j*64 + lane];
        acc += a.x*xv[j].x + a.y*xv[j].y + a.z*xv[j].z + a.w*xv[j].w;
        float4 b = whh[j*64 + lane];
        acc += b.x*hv[j].x + b.y*hv[j].y + b.z*hv[j].z + b.w*hv[j].w;
    }
    acc = wave_reduce(acc);

    __shared__ float gates[4];
    if (lane == 0) gates[wave] = acc + bih[row] + bhh[row];
    __syncthreads();

    if (threadIdx.x == 0) {
        float ig = sigmoidf_(gates[0]);
        float fg = sigmoidf_(gates[1]);
        float gg = tanhf(gates[2]);
        float og = sigmoidf_(gates[3]);
        float c  = fg * c_prev[r] + ig * gg;
        float h  = og * tanhf(c);
        h_ws[r] = h;
        out[HOUT_OFF + layer * HID + r] = h;
        out[COUT_OFF + layer * HID + r] = c;
    }
    __syncthreads();   // gates[] reused by the next layer call
}

__global__ __launch_bounds__(256, 4) void fused_decoder(
    const float* __restrict__ Wih0, const float* __restrict__ Whh0,
    const float* __restrict__ bih0, const float* __restrict__ bhh0,
    const float* __restrict__ Wih1, const float* __restrict__ Whh1,
    const float* __restrict__ bih1, const float* __restrict__ bhh1,
    const float* __restrict__ emb,  const int* __restrict__ word,
    const float* __restrict__ h0,   const float* __restrict__ c0,
    const float* __restrict__ Wout, const float* __restrict__ bout,
    float* __restrict__ out, float* __restrict__ ws)
{
    const int b = blockIdx.x;
    unsigned* bar   = (unsigned*)ws;      // 64 B, zeroed by hipMemsetAsync
    float* h1       = ws + 16;            // HID
    float* h2       = ws + 16 + HID;      // HID
    float* partials = ws + 16 + 2*HID;    // 2*GRID_BLKS

    // ---- phase 1: LSTM layer 0 (x = relu(emb[word])) ----
    lstm_layer(Wih0, Whh0, bih0, bhh0,
               emb + (size_t)word[0] * EMB, true,
               h0, c0, h1, out, 0, b);
    grid_sync(bar, 1u * GRID_BLKS);

    // ---- phase 2: LSTM layer 1 (x = h1) ----
    lstm_layer(Wih1, Whh1, bih1, bhh1,
               h1, false,
               h0 + HID, c0 + HID, h2, out, 1, b);
    grid_sync(bar, 2u * GRID_BLKS);

    // ---- phase 3: logits GEMV, grid-strided over 16-row tiles ----
    const int wave = threadIdx.x >> 6;
    const int lane = threadIdx.x & 63;

    float4 xv[4];
#pragma unroll
    for (int j = 0; j < 4; ++j) xv[j] = ((const float4*)h2)[j*64 + lane];

    float m = -INFINITY, s = 0.f;
    for (int tile = b; tile < NB_LOGITS; tile += GRID_BLKS) {
        const int base = tile * ROWS_PER_BLOCK + wave * 4;
#pragma unroll
        for (int k = 0; k < 4; ++k) {
            const int row = base + k;
            const int rc  = row < VOCAB ? row : VOCAB - 1;  // clamp: keep loads unconditional
            const float4* wr = (const float4*)(Wout + (size_t)rc * HID);
            float acc = 0.f;
#pragma unroll
            for (int j = 0; j < 4; ++j) {
                float4 a = wr[j*64 + lane];
                acc += a.x*xv[j].x + a.y*xv[j].y + a.z*xv[j].z + a.w*xv[j].w;
            }
            acc = wave_reduce(acc);
            if (lane == 0 && row < VOCAB) {
                float logit = acc + bout[row];
                out[row] = logit;
                float nm = fmaxf(m, logit);
                s = s * expf(m - nm) + expf(logit - nm);
                m = nm;
            }
        }
    }

    __shared__ float ms[4], ss[4];
    if (lane == 0) { ms[wave] = m; ss[wave] = s; }
    __syncthreads();
    if (threadIdx.x == 0) {
        float M = ms[0], S = ss[0];   // wave 0 always saw >=1 valid row (b < 1024)
#pragma unroll
        for (int w = 1; w < 4; ++w) {
            float nm = fmaxf(M, ms[w]);
            S = S * expf(M - nm) + ss[w] * expf(ms[w] - nm);
            M = nm;
        }
        partials[2*b]     = M;
        partials[2*b + 1] = S;
    }
    grid_sync(bar, 3u * GRID_BLKS);

    // ---- phase 4: every block redundantly reduces the 1024 partials (L2/L3-hot) ----
    float M = -INFINITY, S = 0.f;
    for (int p = threadIdx.x; p < GRID_BLKS; p += 256) {
        float mm = partials[2*p], sp = partials[2*p + 1];
        float nm = fmaxf(M, mm);
        S = S * expf(M - nm) + sp * expf(mm - nm);
        M = nm;
    }
    __shared__ float msr[256], ssr[256];
    msr[threadIdx.x] = M; ssr[threadIdx.x] = S;
    __syncthreads();
    for (int o = 128; o > 0; o >>= 1) {
        if (threadIdx.x < (unsigned)o) {
            float m2 = msr[threadIdx.x + o], s2 = ssr[threadIdx.x + o];
            float m1 = msr[threadIdx.x];
            float nm = fmaxf(m1, m2);
            ssr[threadIdx.x] = ssr[threadIdx.x] * expf(m1 - nm) + s2 * expf(m2 - nm);
            msr[threadIdx.x] = nm;
        }
        __syncthreads();
    }
    const float lse = msr[0] + logf(ssr[0]);

    // ---- phase 5: in-place log-softmax subtraction ----
    const int idx = b * 256 + (int)threadIdx.x;
    if (idx < VOCAB) out[idx] -= lse;
}

extern "C" void kernel_launch(void* const* d_in, const int* in_sizes, int n_in,
                              void* d_out, int out_size, void* d_ws, size_t ws_size,
                              hipStream_t stream)
{
    const int*   word = (const int*)  d_in[0];
    const float* h0   = (const float*)d_in[1];
    const float* c0   = (const float*)d_in[2];
    const float* emb  = (const float*)d_in[3];
    const float* Wih0 = (const float*)d_in[4];
    const float* Whh0 = (const float*)d_in[5];
    const float* bih0 = (const float*)d_in[6];
    const float* bhh0 = (const float*)d_in[7];
    const float* Wih1 = (const float*)d_in[8];
    const float* Whh1 = (const float*)d_in[9];
    const float* bih1 = (const float*)d_in[10];
    const float* bhh1 = (const float*)d_in[11];
    const float* Wout = (const float*)d_in[12];
    const float* bout = (const float*)d_in[13];

    float* out = (float*)d_out;
    float* ws  = (float*)d_ws;

    // Zero the barrier counter (workspace is re-poisoned between iterations).
    hipMemsetAsync(ws, 0, 64, stream);

    hipLaunchKernelGGL(fused_decoder, dim3(GRID_BLKS), dim3(256), 0, stream,
                       Wih0, Whh0, bih0, bhh0,
                       Wih1, Whh1, bih1, bhh1,
                       emb, word, h0, c0,
                       Wout, bout, out, ws);
}

// Round 3
// 418.894 us; speedup vs baseline: 2.9281x; 2.9281x over previous
//
#include <hip/hip_runtime.h>
#include <math.h>

#define EMB 1024
#define HID 1024
#define VOCAB 50257
#define HOUT_OFF VOCAB
#define COUT_OFF (VOCAB + 2*HID)
#define ROWS_PER_BLOCK 16
#define NB_LOGITS ((VOCAB + ROWS_PER_BLOCK - 1) / ROWS_PER_BLOCK)  // 3142

typedef float f32x4 __attribute__((ext_vector_type(4)));

__device__ __forceinline__ float wave_reduce(float v) {
#pragma unroll
    for (int o = 32; o > 0; o >>= 1) v += __shfl_down(v, o);
    return v;
}

__device__ __forceinline__ float sigmoidf_(float x) { return 1.0f / (1.0f + expf(-x)); }

// One block per hidden unit r. Wave w (0..3) computes gate w (i/f/g/o).
__global__ __launch_bounds__(256) void lstm_gemv(
    const float* __restrict__ Wih, const float* __restrict__ Whh,
    const float* __restrict__ bih, const float* __restrict__ bhh,
    const float* __restrict__ emb, const int* __restrict__ word,
    const float* __restrict__ x_in,            // null for layer 0 (use emb+relu)
    const float* __restrict__ h_prev, const float* __restrict__ c_prev,
    float* __restrict__ h_ws, float* __restrict__ out, int layer)
{
    const int r    = blockIdx.x;          // hidden unit 0..HID-1
    const int wave = threadIdx.x >> 6;    // 0..3 -> gate i/f/g/o
    const int lane = threadIdx.x & 63;
    const int row  = wave * HID + r;

    float4 xv[4], hv[4];
    if (x_in != nullptr) {
#pragma unroll
        for (int j = 0; j < 4; ++j) xv[j] = ((const float4*)x_in)[j*64 + lane];
    } else {
        const float4* e = (const float4*)(emb + (size_t)word[0] * EMB);
#pragma unroll
        for (int j = 0; j < 4; ++j) {
            float4 v = e[j*64 + lane];
            v.x = fmaxf(v.x, 0.f); v.y = fmaxf(v.y, 0.f);
            v.z = fmaxf(v.z, 0.f); v.w = fmaxf(v.w, 0.f);
            xv[j] = v;
        }
    }
#pragma unroll
    for (int j = 0; j < 4; ++j) hv[j] = ((const float4*)h_prev)[j*64 + lane];

    const float4* wih = (const float4*)(Wih + (size_t)row * EMB);
    const float4* whh = (const float4*)(Whh + (size_t)row * HID);
    float acc = 0.f;
#pragma unroll
    for (int j = 0; j < 4; ++j) {
        float4 a = wih[j*64 + lane];
        acc += a.x*xv[j].x + a.y*xv[j].y + a.z*xv[j].z + a.w*xv[j].w;
        float4 b = whh[j*64 + lane];
        acc += b.x*hv[j].x + b.y*hv[j].y + b.z*hv[j].z + b.w*hv[j].w;
    }
    acc = wave_reduce(acc);

    __shared__ float gates[4];
    if (lane == 0) gates[wave] = acc + bih[row] + bhh[row];
    __syncthreads();

    if (threadIdx.x == 0) {
        float ig = sigmoidf_(gates[0]);
        float fg = sigmoidf_(gates[1]);
        float gg = tanhf(gates[2]);
        float og = sigmoidf_(gates[3]);
        float c  = fg * c_prev[r] + ig * gg;
        float h  = og * tanhf(c);
        h_ws[r] = h;
        out[HOUT_OFF + layer * HID + r] = h;
        out[COUT_OFF + layer * HID + r] = c;
    }
}

// logits[row] = dot(W_out[row], h2) + b_out[row]; 4 rows per wave, 16 per
// block. Each block also emits an online-softmax partial (max, sumexp).
// W rows are streamed non-temporally (read-once, L3 gets evicted by the
// harness's inter-iteration fills anyway).
__global__ __launch_bounds__(256) void logits_gemv(
    const float* __restrict__ W, const float* __restrict__ b,
    const float* __restrict__ x, float* __restrict__ out,
    float* __restrict__ partials)
{
    const int wave = threadIdx.x >> 6;
    const int lane = threadIdx.x & 63;

    f32x4 xv[4];
#pragma unroll
    for (int j = 0; j < 4; ++j) xv[j] = ((const f32x4*)x)[j*64 + lane];

    float m = -INFINITY, s = 0.f;
    const int base = blockIdx.x * ROWS_PER_BLOCK + wave * 4;
#pragma unroll
    for (int k = 0; k < 4; ++k) {
        int row = base + k;
        if (row >= VOCAB) break;   // wave-uniform
        const f32x4* wr = (const f32x4*)(W + (size_t)row * HID);
        float acc = 0.f;
#pragma unroll
        for (int j = 0; j < 4; ++j) {
            f32x4 a = __builtin_nontemporal_load(wr + j*64 + lane);
            acc += a.x*xv[j].x + a.y*xv[j].y + a.z*xv[j].z + a.w*xv[j].w;
        }
        acc = wave_reduce(acc);
        if (lane == 0) {
            float logit = acc + b[row];
            out[row] = logit;
            float nm = fmaxf(m, logit);
            s = s * expf(m - nm) + expf(logit - nm);
            m = nm;
        }
    }

    __shared__ float ms[4], ss[4];
    if (lane == 0) { ms[wave] = m; ss[wave] = s; }
    __syncthreads();
    if (threadIdx.x == 0) {
        float M = ms[0], S = ss[0];     // wave 0 always has >=1 valid row
#pragma unroll
        for (int w = 1; w < 4; ++w) {
            float nm = fmaxf(M, ms[w]);
            S = S * expf(M - nm) + ss[w] * expf(ms[w] - nm);
            M = nm;
        }
        partials[2 * blockIdx.x]     = M;
        partials[2 * blockIdx.x + 1] = S;
    }
}

// Fused softmax_combine + subtraction: every block redundantly reduces the
// NB_LOGITS (m,s) partials (25 KB, L2-hot) then subtracts the LSE from its
// 256 logits. Removes one dispatch + one dependent round-trip.
__global__ __launch_bounds__(256) void lse_sub(
    float* __restrict__ out, const float* __restrict__ partials, int nb)
{
    float M = -INFINITY, S = 0.f;
    for (int p = threadIdx.x; p < nb; p += 256) {
        float m = partials[2*p], s = partials[2*p + 1];
        float nm = fmaxf(M, m);
        S = S * expf(M - nm) + s * expf(m - nm);
        M = nm;
    }
    __shared__ float ms[256], ss[256];
    ms[threadIdx.x] = M; ss[threadIdx.x] = S;
    __syncthreads();
    for (int o = 128; o > 0; o >>= 1) {
        if (threadIdx.x < (unsigned)o) {
            float m2 = ms[threadIdx.x + o], s2 = ss[threadIdx.x + o];
            float m1 = ms[threadIdx.x];
            float nm = fmaxf(m1, m2);
            ss[threadIdx.x] = ss[threadIdx.x] * expf(m1 - nm) + s2 * expf(m2 - nm);
            ms[threadIdx.x] = nm;
        }
        __syncthreads();
    }
    const float lse = ms[0] + logf(ss[0]);

    const int i = blockIdx.x * 256 + (int)threadIdx.x;
    if (i < VOCAB) out[i] -= lse;
}

extern "C" void kernel_launch(void* const* d_in, const int* in_sizes, int n_in,
                              void* d_out, int out_size, void* d_ws, size_t ws_size,
                              hipStream_t stream)
{
    const int*   word = (const int*)  d_in[0];
    const float* h0   = (const float*)d_in[1];
    const float* c0   = (const float*)d_in[2];
    const float* emb  = (const float*)d_in[3];
    const float* Wih0 = (const float*)d_in[4];
    const float* Whh0 = (const float*)d_in[5];
    const float* bih0 = (const float*)d_in[6];
    const float* bhh0 = (const float*)d_in[7];
    const float* Wih1 = (const float*)d_in[8];
    const float* Whh1 = (const float*)d_in[9];
    const float* bih1 = (const float*)d_in[10];
    const float* bhh1 = (const float*)d_in[11];
    const float* Wout = (const float*)d_in[12];
    const float* bout = (const float*)d_in[13];

    float* out = (float*)d_out;
    float* ws  = (float*)d_ws;
    float* h1       = ws;                      // HID floats
    float* h2       = ws + HID;                // HID floats
    float* partials = ws + 2 * HID;            // 2*NB_LOGITS floats

    lstm_gemv<<<HID, 256, 0, stream>>>(Wih0, Whh0, bih0, bhh0, emb, word,
                                       nullptr, h0, c0, h1, out, 0);
    lstm_gemv<<<HID, 256, 0, stream>>>(Wih1, Whh1, bih1, bhh1, emb, word,
                                       h1, h0 + HID, c0 + HID, h2, out, 1);
    logits_gemv<<<NB_LOGITS, 256, 0, stream>>>(Wout, bout, h2, out, partials);
    lse_sub<<<(VOCAB + 255) / 256, 256, 0, stream>>>(out, partials, NB_LOGITS);
}

// Round 4
// 412.421 us; speedup vs baseline: 2.9741x; 1.0157x over previous
//
#include <hip/hip_runtime.h>
#include <math.h>

#define EMB 1024
#define HID 1024
#define VOCAB 50257
#define HOUT_OFF VOCAB
#define COUT_OFF (VOCAB + 2*HID)
#define ROWS_PER_BLOCK 16
#define NB_LOGITS ((VOCAB + ROWS_PER_BLOCK - 1) / ROWS_PER_BLOCK)  // 3142

typedef float f32x4 __attribute__((ext_vector_type(4)));

__device__ __forceinline__ float wave_reduce(float v) {
#pragma unroll
    for (int o = 32; o > 0; o >>= 1) v += __shfl_down(v, o);
    return v;
}

__device__ __forceinline__ float sigmoidf_(float x) { return 1.0f / (1.0f + expf(-x)); }

// Dispatch 1, grid = 2*HID blocks.
//  blocks [0, HID):      layer-0 LSTM for hidden unit r (x = relu(emb[word])).
//  blocks [HID, 2*HID):  input-independent half of layer-1's gates:
//                        rpart[row] = Whh1[row].h0[1] + bih1[row] + bhh1[row]
// The second half has no dependency on the first -> free overlap, and it
// removes 16.8 MB from the serial layer-1 dispatch.
__global__ __launch_bounds__(256) void lstm0_and_rec1(
    const float* __restrict__ Wih0, const float* __restrict__ Whh0,
    const float* __restrict__ bih0, const float* __restrict__ bhh0,
    const float* __restrict__ Whh1, const float* __restrict__ bih1,
    const float* __restrict__ bhh1,
    const float* __restrict__ emb,  const int* __restrict__ word,
    const float* __restrict__ h0,   const float* __restrict__ c0,
    float* __restrict__ h1, float* __restrict__ rpart,
    float* __restrict__ out)
{
    const int wave = threadIdx.x >> 6;    // 0..3 -> gate i/f/g/o
    const int lane = threadIdx.x & 63;

    if (blockIdx.x < HID) {
        // ---- layer-0 LSTM ----
        const int r   = blockIdx.x;
        const int row = wave * HID + r;

        f32x4 xv[4], hv[4];
        const f32x4* e = (const f32x4*)(emb + (size_t)word[0] * EMB);
#pragma unroll
        for (int j = 0; j < 4; ++j) {
            f32x4 v = e[j*64 + lane];
            v.x = fmaxf(v.x, 0.f); v.y = fmaxf(v.y, 0.f);
            v.z = fmaxf(v.z, 0.f); v.w = fmaxf(v.w, 0.f);
            xv[j] = v;
            hv[j] = ((const f32x4*)h0)[j*64 + lane];
        }

        const f32x4* wih = (const f32x4*)(Wih0 + (size_t)row * EMB);
        const f32x4* whh = (const f32x4*)(Whh0 + (size_t)row * HID);
        float acc = 0.f;
#pragma unroll
        for (int j = 0; j < 4; ++j) {
            f32x4 a = __builtin_nontemporal_load(wih + j*64 + lane);
            acc += a.x*xv[j].x + a.y*xv[j].y + a.z*xv[j].z + a.w*xv[j].w;
            f32x4 b = __builtin_nontemporal_load(whh + j*64 + lane);
            acc += b.x*hv[j].x + b.y*hv[j].y + b.z*hv[j].z + b.w*hv[j].w;
        }
        acc = wave_reduce(acc);

        __shared__ float gates[4];
        if (lane == 0) gates[wave] = acc + bih0[row] + bhh0[row];
        __syncthreads();

        if (threadIdx.x == 0) {
            float ig = sigmoidf_(gates[0]);
            float fg = sigmoidf_(gates[1]);
            float gg = tanhf(gates[2]);
            float og = sigmoidf_(gates[3]);
            float c  = fg * c0[r] + ig * gg;
            float h  = og * tanhf(c);
            h1[r] = h;
            out[HOUT_OFF + r] = h;
            out[COUT_OFF + r] = c;
        }
    } else {
        // ---- layer-1 recurrent partial (depends only on h0[1]) ----
        const int r   = blockIdx.x - HID;
        const int row = wave * HID + r;

        f32x4 hv[4];
#pragma unroll
        for (int j = 0; j < 4; ++j) hv[j] = ((const f32x4*)(h0 + HID))[j*64 + lane];

        const f32x4* whh = (const f32x4*)(Whh1 + (size_t)row * HID);
        float acc = 0.f;
#pragma unroll
        for (int j = 0; j < 4; ++j) {
            f32x4 b = __builtin_nontemporal_load(whh + j*64 + lane);
            acc += b.x*hv[j].x + b.y*hv[j].y + b.z*hv[j].z + b.w*hv[j].w;
        }
        acc = wave_reduce(acc);
        if (lane == 0) rpart[row] = acc + bih1[row] + bhh1[row];
    }
}

// Dispatch 2: layer-1 LSTM, gates = Wih1.h1 + rpart  (only 16.8 MB of reads).
__global__ __launch_bounds__(256) void lstm1_gemv(
    const float* __restrict__ Wih1, const float* __restrict__ h1,
    const float* __restrict__ rpart, const float* __restrict__ c_prev,
    float* __restrict__ h2, float* __restrict__ out)
{
    const int r    = blockIdx.x;
    const int wave = threadIdx.x >> 6;
    const int lane = threadIdx.x & 63;
    const int row  = wave * HID + r;

    f32x4 xv[4];
#pragma unroll
    for (int j = 0; j < 4; ++j) xv[j] = ((const f32x4*)h1)[j*64 + lane];

    const f32x4* wih = (const f32x4*)(Wih1 + (size_t)row * HID);
    float acc = 0.f;
#pragma unroll
    for (int j = 0; j < 4; ++j) {
        f32x4 a = __builtin_nontemporal_load(wih + j*64 + lane);
        acc += a.x*xv[j].x + a.y*xv[j].y + a.z*xv[j].z + a.w*xv[j].w;
    }
    acc = wave_reduce(acc);

    __shared__ float gates[4];
    if (lane == 0) gates[wave] = acc + rpart[row];
    __syncthreads();

    if (threadIdx.x == 0) {
        float ig = sigmoidf_(gates[0]);
        float fg = sigmoidf_(gates[1]);
        float gg = tanhf(gates[2]);
        float og = sigmoidf_(gates[3]);
        float c  = fg * c_prev[r] + ig * gg;
        float h  = og * tanhf(c);
        h2[r] = h;
        out[HOUT_OFF + HID + r] = h;
        out[COUT_OFF + HID + r] = c;
    }
}

// logits[row] = dot(W_out[row], h2) + b_out[row]; 4 rows per wave, 16 per
// block; per-block online-softmax partial (max, sumexp). W streamed nt.
__global__ __launch_bounds__(256) void logits_gemv(
    const float* __restrict__ W, const float* __restrict__ b,
    const float* __restrict__ x, float* __restrict__ out,
    float* __restrict__ partials)
{
    const int wave = threadIdx.x >> 6;
    const int lane = threadIdx.x & 63;

    f32x4 xv[4];
#pragma unroll
    for (int j = 0; j < 4; ++j) xv[j] = ((const f32x4*)x)[j*64 + lane];

    float m = -INFINITY, s = 0.f;
    const int base = blockIdx.x * ROWS_PER_BLOCK + wave * 4;
#pragma unroll
    for (int k = 0; k < 4; ++k) {
        int row = base + k;
        if (row >= VOCAB) break;   // wave-uniform
        const f32x4* wr = (const f32x4*)(W + (size_t)row * HID);
        float acc = 0.f;
#pragma unroll
        for (int j = 0; j < 4; ++j) {
            f32x4 a = __builtin_nontemporal_load(wr + j*64 + lane);
            acc += a.x*xv[j].x + a.y*xv[j].y + a.z*xv[j].z + a.w*xv[j].w;
        }
        acc = wave_reduce(acc);
        if (lane == 0) {
            float logit = acc + b[row];
            out[row] = logit;
            float nm = fmaxf(m, logit);
            s = s * expf(m - nm) + expf(logit - nm);
            m = nm;
        }
    }

    __shared__ float ms[4], ss[4];
    if (lane == 0) { ms[wave] = m; ss[wave] = s; }
    __syncthreads();
    if (threadIdx.x == 0) {
        float M = ms[0], S = ss[0];     // wave 0 always has >=1 valid row
#pragma unroll
        for (int w = 1; w < 4; ++w) {
            float nm = fmaxf(M, ms[w]);
            S = S * expf(M - nm) + ss[w] * expf(ms[w] - nm);
            M = nm;
        }
        partials[2 * blockIdx.x]     = M;
        partials[2 * blockIdx.x + 1] = S;
    }
}

// Fused combine+subtract: each block redundantly reduces the NB_LOGITS
// (m,s) partials (25 KB, L2-hot) then subtracts the LSE from its 256 logits.
__global__ __launch_bounds__(256) void lse_sub(
    float* __restrict__ out, const float* __restrict__ partials, int nb)
{
    float M = -INFINITY, S = 0.f;
    for (int p = threadIdx.x; p < nb; p += 256) {
        float m = partials[2*p], s = partials[2*p + 1];
        float nm = fmaxf(M, m);
        S = S * expf(M - nm) + s * expf(m - nm);
        M = nm;
    }
    __shared__ float ms[256], ss[256];
    ms[threadIdx.x] = M; ss[threadIdx.x] = S;
    __syncthreads();
    for (int o = 128; o > 0; o >>= 1) {
        if (threadIdx.x < (unsigned)o) {
            float m2 = ms[threadIdx.x + o], s2 = ss[threadIdx.x + o];
            float m1 = ms[threadIdx.x];
            float nm = fmaxf(m1, m2);
            ss[threadIdx.x] = ss[threadIdx.x] * expf(m1 - nm) + s2 * expf(m2 - nm);
            ms[threadIdx.x] = nm;
        }
        __syncthreads();
    }
    const float lse = ms[0] + logf(ss[0]);

    const int i = blockIdx.x * 256 + (int)threadIdx.x;
    if (i < VOCAB) out[i] -= lse;
}

extern "C" void kernel_launch(void* const* d_in, const int* in_sizes, int n_in,
                              void* d_out, int out_size, void* d_ws, size_t ws_size,
                              hipStream_t stream)
{
    const int*   word = (const int*)  d_in[0];
    const float* h0   = (const float*)d_in[1];
    const float* c0   = (const float*)d_in[2];
    const float* emb  = (const float*)d_in[3];
    const float* Wih0 = (const float*)d_in[4];
    const float* Whh0 = (const float*)d_in[5];
    const float* bih0 = (const float*)d_in[6];
    const float* bhh0 = (const float*)d_in[7];
    const float* Wih1 = (const float*)d_in[8];
    const float* Whh1 = (const float*)d_in[9];
    const float* bih1 = (const float*)d_in[10];
    const float* bhh1 = (const float*)d_in[11];
    const float* Wout = (const float*)d_in[12];
    const float* bout = (const float*)d_in[13];

    float* out = (float*)d_out;
    float* ws  = (float*)d_ws;
    float* h1       = ws;                      // HID floats
    float* h2       = ws + HID;                // HID floats
    float* rpart    = ws + 2 * HID;            // 4*HID floats
    float* partials = ws + 6 * HID;            // 2*NB_LOGITS floats

    lstm0_and_rec1<<<2 * HID, 256, 0, stream>>>(
        Wih0, Whh0, bih0, bhh0, Whh1, bih1, bhh1,
        emb, word, h0, c0, h1, rpart, out);
    lstm1_gemv<<<HID, 256, 0, stream>>>(Wih1, h1, rpart, c0 + HID, h2, out);
    logits_gemv<<<NB_LOGITS, 256, 0, stream>>>(Wout, bout, h2, out, partials);
    lse_sub<<<(VOCAB + 255) / 256, 256, 0, stream>>>(out, partials, NB_LOGITS);
}